// Round 9
// baseline (434.980 us; speedup 1.0000x reference)
//
#include <hip/hip_runtime.h>
#include <hip/hip_bf16.h>

// DimeNet-like GNN, f32 in/out (flag=1 confirmed rounds 2-7; ws ~268MB per
// round-8 WRITE_SIZE evidence). Round 8:
//  - payload-sorted arrays (k_srt, cbf_s f32, src_s) built in scatter: the
//    tri/edge segment loops become streaming uniform loads + ONE gather level
//  - dispatch count 28 -> 17: fused hist2/scatter2/setup, per-layer 6->4
//    (lin2out computes Hh+Hs in one pass; Ad fused into edge kernel as f32
//    shfl-GEMV; node MLP two stages fused via wave-local LDS transpose),
//    pool+head fused, hinit eliminated (layer-0 reads x via dual-dtype loads)

#define N_NODES 16000
#define N_EDGES 256000
#define N_TRI   640000
#define N_B     128
#define OUT_DIM 32
#define L_LAYERS 3

typedef __hip_bfloat16 bf16;
typedef short s8v __attribute__((ext_vector_type(8)));
typedef float f4v __attribute__((ext_vector_type(4)));

__device__ __forceinline__ float ldx(const void* p, size_t i, int f) {
    if (f) return ((const float*)p)[i];
    return __bfloat162float(((const bf16*)p)[i]);
}

// ---- bf16 split helpers ----
__device__ __forceinline__ unsigned short f2bf_rne(float x) {
    unsigned int u = __float_as_uint(x);
    unsigned int r = (u + 0x7FFFu + ((u >> 16) & 1u)) >> 16;
    return (unsigned short)r;
}
__device__ __forceinline__ float bf2f(unsigned short b) {
    return __uint_as_float(((unsigned int)b) << 16);
}
__device__ __forceinline__ void split2(float a, unsigned short& h, unsigned short& l) {
    h = f2bf_rne(a);
    l = f2bf_rne(a - bf2f(h));
}
__device__ __forceinline__ void make_afrag(const float* av, s8v& ah, s8v& al) {
    #pragma unroll
    for (int j = 0; j < 8; j++) {
        unsigned short h, l; split2(av[j], h, l);
        ah[j] = (short)h; al[j] = (short)l;
    }
}

// stage W (64-col) into split hi/lo fragment order; KS K-steps of 32
__device__ __forceinline__ void stageW(const void* W, size_t offW, int KS, int f,
                                       unsigned short* sBhi, unsigned short* sBlo) {
    for (int idx = threadIdx.x; idx < KS * 2048; idx += 256) {
        int jj = idx & 7, ln = (idx >> 3) & 63, nt = (idx >> 9) & 3, ks = idx >> 11;
        int k = ks * 32 + (ln >> 4) * 8 + jj;
        int n = nt * 16 + (ln & 15);
        float w = ldx(W, offW + (size_t)k * 64 + n, f);
        unsigned short h_, l_; split2(w, h_, l_);
        sBhi[idx] = h_; sBlo[idx] = l_;
    }
}

// 3-product split MFMA over 4 N-tiles for one K-step
__device__ __forceinline__ void mfma3(const unsigned short* sBhi, const unsigned short* sBlo,
                                      int ks, int lane, const s8v& ah, const s8v& al,
                                      f4v acc[4]) {
    #pragma unroll
    for (int nt = 0; nt < 4; nt++) {
        s8v bh = *(const s8v*)&sBhi[(ks * 4 + nt) * 512 + lane * 8];
        s8v bl = *(const s8v*)&sBlo[(ks * 4 + nt) * 512 + lane * 8];
        acc[nt] = __builtin_amdgcn_mfma_f32_16x16x32_bf16(ah, bh, acc[nt], 0, 0, 0);
        acc[nt] = __builtin_amdgcn_mfma_f32_16x16x32_bf16(al, bh, acc[nt], 0, 0, 0);
        acc[nt] = __builtin_amdgcn_mfma_f32_16x16x32_bf16(ah, bl, acc[nt], 0, 0, 0);
    }
}

// dual-dtype A-row load: 8 consecutive elements at (row, ks*32+quad*8)
__device__ __forceinline__ void ldrow8(const void* A, int fa, size_t row, int ks,
                                       int quad, float av[8]) {
    if (fa) {
        const float* p = (const float*)A + row * 64 + ks * 32 + quad * 8;
        float4 x0 = ((const float4*)p)[0], x1 = ((const float4*)p)[1];
        av[0] = x0.x; av[1] = x0.y; av[2] = x0.z; av[3] = x0.w;
        av[4] = x1.x; av[5] = x1.y; av[6] = x1.z; av[7] = x1.w;
    } else {
        const bf16* p = (const bf16*)A + row * 64 + ks * 32 + quad * 8;
        #pragma unroll
        for (int j = 0; j < 8; j++) av[j] = __bfloat162float(p[j]);
    }
}

// ---------------------------------------------------------------- diag helpers
__global__ void k_probe(const void* __restrict__ rbf, int* __restrict__ flag) {
    if (threadIdx.x == 0 && blockIdx.x == 0) {
        const float* p = (const float*)rbf;
        int good = 0;
        for (int i = 0; i < 256; i++) {
            float v = fabsf(p[i]);
            if (v > 1e-4f && v < 100.0f) good++;
        }
        *flag = (good > 192) ? 1 : 0;
    }
}

__global__ void k_fill(void* __restrict__ out, const int* __restrict__ flag,
                       float val, int n) {
    int i = blockIdx.x * blockDim.x + threadIdx.x;
    if (i < n) {
        if (*flag) ((float*)out)[i] = val;
        else       ((bf16*)out)[i] = __float2bfloat16(val);
    }
}

// ---------------------------------------------------------------- setup: zero cursors + dtype probe
__global__ void k_setup(const void* __restrict__ rbf, int* __restrict__ flag,
                        int* __restrict__ cur) {  // cur = cur_t .. cur_e contiguous, 2*N ints
    int i = blockIdx.x * blockDim.x + threadIdx.x;
    int stride = gridDim.x * blockDim.x;
    for (; i < 2 * N_NODES; i += stride) cur[i] = 0;
    if (blockIdx.x == 0 && threadIdx.x == 0) {
        const float* p = (const float*)rbf;
        int good = 0;
        for (int q = 0; q < 256; q++) {
            float v = fabsf(p[q]);
            if (v > 1e-4f && v < 100.0f) good++;
        }
        *flag = (good > 192) ? 1 : 0;
    }
}

// ---------------------------------------------------------------- fused histograms
__global__ void k_hist2(const int* __restrict__ j_idx, const int* __restrict__ edge_index,
                        int* __restrict__ cur_t, int* __restrict__ cur_e) {
    const int TB = (N_TRI + 255) / 256;  // 2500
    if ((int)blockIdx.x < TB) {
        int i = blockIdx.x * 256 + threadIdx.x;
        if (i < N_TRI) {
            unsigned j = (unsigned)j_idx[i];
            if (j < N_NODES) atomicAdd(&cur_t[j], 1);
        }
    } else {
        int i = (blockIdx.x - TB) * 256 + threadIdx.x;
        if (i < N_EDGES) {
            unsigned d = (unsigned)edge_index[N_EDGES + i];
            if (d < N_NODES) atomicAdd(&cur_e[d], 1);
        }
    }
}

// ---------------------------------------------------------------- scan (2 arrays)
__global__ __launch_bounds__(256) void k_scan2(int* __restrict__ a, int* __restrict__ b) {
    int* cnt = (blockIdx.x == 0) ? a : b;
    __shared__ int part[256];
    int tid = threadIdx.x;
    const int PER = (N_NODES + 255) / 256;  // 63
    int base = tid * PER;
    int s = 0;
    for (int i = 0; i < PER; i++) {
        int idx = base + i;
        if (idx < N_NODES) s += cnt[idx];
    }
    part[tid] = s;
    __syncthreads();
    for (int d = 1; d < 256; d <<= 1) {
        int v = (tid >= d) ? part[tid - d] : 0;
        __syncthreads();
        part[tid] += v;
        __syncthreads();
    }
    int run = (tid > 0) ? part[tid - 1] : 0;
    for (int i = 0; i < PER; i++) {
        int idx = base + i;
        if (idx < N_NODES) {
            int v = cnt[idx];
            cnt[idx] = run;
            run += v;
        }
    }
}

// ---------------------------------------------------------------- fused scatter + payload gather
__global__ void k_scatter2(const int* __restrict__ j_idx, const int* __restrict__ k_idx,
                           const void* __restrict__ cbf, const int* __restrict__ edge_index,
                           int* __restrict__ cur_t, int* __restrict__ cur_e,
                           int* __restrict__ k_srt, float* __restrict__ cbf_s,
                           int* __restrict__ src_s, const int* __restrict__ flag) {
    const int TB = (N_TRI + 255) / 256;  // 2500
    int f = *flag;
    if ((int)blockIdx.x < TB) {
        int i = blockIdx.x * 256 + threadIdx.x;
        if (i < N_TRI) {
            unsigned j = (unsigned)j_idx[i];
            if (j < N_NODES) {
                int pos = atomicAdd(&cur_t[j], 1);
                if ((unsigned)pos < (unsigned)N_TRI) {
                    unsigned k = (unsigned)k_idx[i]; if (k >= N_NODES) k = 0;
                    k_srt[pos] = (int)k;
                    #pragma unroll
                    for (int q = 0; q < 6; q++)
                        cbf_s[(size_t)pos * 6 + q] = ldx(cbf, (size_t)i * 6 + q, f);
                }
            }
        }
    } else {
        int e = (blockIdx.x - TB) * 256 + threadIdx.x;
        if (e < N_EDGES) {
            unsigned d = (unsigned)edge_index[N_EDGES + e];
            if (d < N_NODES) {
                int pos = atomicAdd(&cur_e[d], 1);
                if ((unsigned)pos < (unsigned)N_EDGES) {
                    unsigned s = (unsigned)edge_index[e]; if (s >= N_NODES) s = 0;
                    src_s[pos] = (int)s;
                }
            }
        }
    }
    // after this kernel, cur_t/cur_e hold bucket END offsets
}

// ---------------------------------------------------------------- lin2out: Hh and Hs in one pass
// X = A1 @ W1[0:64] + b1 ; Y = A1 @ W2[0:64] + b2  (pre-activation, K=64)
__global__ __launch_bounds__(256) void k_lin2out(
    const void* __restrict__ A1, int a1ws,
    const void* __restrict__ W1, size_t offW1, const void* __restrict__ b1,
    const void* __restrict__ W2, size_t offW2, const void* __restrict__ b2,
    size_t offB, const int* __restrict__ flag,
    float* __restrict__ X, float* __restrict__ Y) {
    __shared__ unsigned short h1[2 * 2048], l1[2 * 2048];
    __shared__ unsigned short h2[2 * 2048], l2[2 * 2048];
    __shared__ float sB1[64], sB2[64];
    int f = *flag;
    int fa = a1ws ? 1 : f;
    stageW(W1, offW1, 2, f, h1, l1);
    stageW(W2, offW2, 2, f, h2, l2);
    if (threadIdx.x < 64) {
        sB1[threadIdx.x] = ldx(b1, offB + threadIdx.x, f);
        sB2[threadIdx.x] = ldx(b2, offB + threadIdx.x, f);
    }
    __syncthreads();
    int lane = threadIdx.x & 63;
    int quad = lane >> 4;
    int m = lane & 15;
    int tile = blockIdx.x * 4 + (threadIdx.x >> 6);  // grid 250 -> 1000 waves = NT
    int row = tile * 16 + m;
    f4v accH[4], accS[4];
    #pragma unroll
    for (int nt = 0; nt < 4; nt++) {
        float bh = sB1[nt * 16 + m], bs = sB2[nt * 16 + m];
        accH[nt] = (f4v){bh, bh, bh, bh};
        accS[nt] = (f4v){bs, bs, bs, bs};
    }
    float av[8]; s8v ah, al;
    #pragma unroll
    for (int ks = 0; ks < 2; ks++) {
        ldrow8(A1, fa, row, ks, quad, av);
        make_afrag(av, ah, al);
        mfma3(h1, l1, ks, lane, ah, al, accH);
        mfma3(h2, l2, ks, lane, ah, al, accS);
    }
    #pragma unroll
    for (int r = 0; r < 4; r++) {
        size_t rr = (size_t)(tile * 16 + quad * 4 + r) * 64 + m;
        #pragma unroll
        for (int nt = 0; nt < 4; nt++) {
            X[rr + nt * 16] = accH[nt][r];
            Y[rr + nt * 16] = accS[nt][r];
        }
    }
}

// ---------------------------------------------------------------- triplet segment sum
// wave per node j: agg_e[j] = sum_p relu(Hh[k_srt[p]] + rbf[j]@W1r + cbf_s[p]@W1c)
__global__ __launch_bounds__(256) void k_tri_seg(
    const int* __restrict__ ends, const int* __restrict__ k_srt,
    const float* __restrict__ cbf_s, const float* __restrict__ Hh,
    const void* __restrict__ rbf, const void* __restrict__ W1, size_t offW,
    const int* __restrict__ flag, float* __restrict__ agg_e) {
    int f = *flag;
    int c = threadIdx.x & 63;
    float wr[6], wc[6];
    #pragma unroll
    for (int q = 0; q < 6; q++) {
        wr[q] = ldx(W1, offW + (size_t)(64 + q) * 64 + c, f);
        wc[q] = ldx(W1, offW + (size_t)(70 + q) * 64 + c, f);
    }
    int j = blockIdx.x * 4 + (threadIdx.x >> 6);  // grid 4000 -> exactly N waves
    int p0 = (j == 0) ? 0 : ends[j - 1];
    int p1 = ends[j];
    if (p0 < 0) p0 = 0; if (p0 > N_TRI) p0 = N_TRI;
    if (p1 < p0) p1 = p0; if (p1 > N_TRI) p1 = N_TRI;
    float rb = 0.f;
    #pragma unroll
    for (int q = 0; q < 6; q++)
        rb += ldx(rbf, (size_t)j * 6 + q, f) * wr[q];
    float s = 0.f;
    for (int p = p0; p < p1; p += 8) {
        int kk[8];
        float hv[8];
        #pragma unroll
        for (int i = 0; i < 8; i++)
            kk[i] = (p + i < p1) ? k_srt[p + i] : 0;
        #pragma unroll
        for (int i = 0; i < 8; i++)
            hv[i] = Hh[(size_t)kk[i] * 64 + c];
        #pragma unroll
        for (int i = 0; i < 8; i++) {
            if (p + i >= p1) continue;
            float v = hv[i] + rb;
            #pragma unroll
            for (int q = 0; q < 6; q++)
                v += cbf_s[(size_t)(p + i) * 6 + q] * wc[q];
            s += fmaxf(v, 0.f);
        }
    }
    agg_e[(size_t)j * 64 + c] = s;
}

// ---------------------------------------------------------------- edge segment sum + fused Ad
// wave per node d: ad = agg_e[d] @ W2a (f32 shfl-GEMV, W2a in LDS);
// aggr[d] = sum_p relu(Hs[src_s[p]] + ad). Plain store.
__global__ __launch_bounds__(256) void k_edge_f(
    const int* __restrict__ ends, const int* __restrict__ src_s,
    const float* __restrict__ Hs, const float* __restrict__ agg_e,
    const void* __restrict__ W2, size_t offW2a, const int* __restrict__ flag,
    float* __restrict__ aggr) {
    __shared__ float sW[64 * 64];
    int f = *flag;
    for (int idx = threadIdx.x; idx < 4096; idx += 256)
        sW[idx] = ldx(W2, offW2a + idx, f);
    __syncthreads();
    int c = threadIdx.x & 63;
    int d = blockIdx.x * 4 + (threadIdx.x >> 6);  // grid 4000 -> exactly N waves
    int p0 = (d == 0) ? 0 : ends[d - 1];
    int p1 = ends[d];
    if (p0 < 0) p0 = 0; if (p0 > N_EDGES) p0 = N_EDGES;
    if (p1 < p0) p1 = p0; if (p1 > N_EDGES) p1 = N_EDGES;
    float av = agg_e[(size_t)d * 64 + c];
    float ad = 0.f;
    #pragma unroll
    for (int k = 0; k < 64; k++)
        ad += __shfl(av, k) * sW[k * 64 + c];
    float s = 0.f;
    for (int p = p0; p < p1; p += 8) {
        int ss[8];
        float hv[8];
        #pragma unroll
        for (int i = 0; i < 8; i++)
            ss[i] = (p + i < p1) ? src_s[p + i] : 0;
        #pragma unroll
        for (int i = 0; i < 8; i++)
            hv[i] = Hs[(size_t)ss[i] * 64 + c];
        #pragma unroll
        for (int i = 0; i < 8; i++)
            if (p + i < p1) s += fmaxf(hv[i] + ad, 0.f);
    }
    aggr[(size_t)d * 64 + c] = s;
}

// ---------------------------------------------------------------- fused node MLP (2 stages)
// h' = relu([A1 | aggr] @ Wn1 + bn1) @ Wn2 + bn2; z transposed via wave-local LDS.
__global__ __launch_bounds__(256) void k_node_f(
    const void* __restrict__ A1, int a1ws, const float* __restrict__ aggr,
    const void* __restrict__ Wn1, const void* __restrict__ bn1,
    const void* __restrict__ Wn2, const void* __restrict__ bn2,
    size_t offW1, size_t offB, size_t offW2,
    const int* __restrict__ flag, float* __restrict__ hout) {
    __shared__ unsigned short s1h[4 * 2048], s1l[4 * 2048];
    __shared__ unsigned short s2h[2 * 2048], s2l[2 * 2048];
    __shared__ float sB1[64], sB2[64];
    __shared__ float zbuf[4][16 * 68];  // stride 68 breaks bank alignment
    int f = *flag;
    int fa = a1ws ? 1 : f;
    stageW(Wn1, offW1, 4, f, s1h, s1l);
    stageW(Wn2, offW2, 2, f, s2h, s2l);
    if (threadIdx.x < 64) {
        sB1[threadIdx.x] = ldx(bn1, offB + threadIdx.x, f);
        sB2[threadIdx.x] = ldx(bn2, offB + threadIdx.x, f);
    }
    __syncthreads();
    int lane = threadIdx.x & 63;
    int quad = lane >> 4;
    int m = lane & 15;
    int w = threadIdx.x >> 6;
    int tile = blockIdx.x * 4 + w;  // grid 250 -> 1000 waves = NT, one tile each
    int row = tile * 16 + m;
    f4v acc[4];
    #pragma unroll
    for (int nt = 0; nt < 4; nt++) {
        float b = sB1[nt * 16 + m];
        acc[nt] = (f4v){b, b, b, b};
    }
    float av[8]; s8v ah, al;
    #pragma unroll
    for (int ks = 0; ks < 2; ks++) {
        ldrow8(A1, fa, row, ks, quad, av);
        make_afrag(av, ah, al);
        mfma3(s1h, s1l, ks, lane, ah, al, acc);
    }
    #pragma unroll
    for (int ks = 0; ks < 2; ks++) {
        ldrow8(aggr, 1, row, ks, quad, av);
        make_afrag(av, ah, al);
        mfma3(s1h, s1l, 2 + ks, lane, ah, al, acc);
    }
    // z = relu(acc) -> LDS (C-layout positions)
    #pragma unroll
    for (int r = 0; r < 4; r++)
        #pragma unroll
        for (int nt = 0; nt < 4; nt++)
            zbuf[w][(quad * 4 + r) * 68 + nt * 16 + m] = fmaxf(acc[nt][r], 0.f);
    __syncthreads();  // uniform: every wave has exactly one tile
    // stage 2: h' = z @ Wn2 + bn2
    f4v acc2[4];
    #pragma unroll
    for (int nt = 0; nt < 4; nt++) {
        float b = sB2[nt * 16 + m];
        acc2[nt] = (f4v){b, b, b, b};
    }
    #pragma unroll
    for (int ks = 0; ks < 2; ks++) {
        #pragma unroll
        for (int jx = 0; jx < 8; jx++)
            av[jx] = zbuf[w][m * 68 + ks * 32 + quad * 8 + jx];
        make_afrag(av, ah, al);
        mfma3(s2h, s2l, ks, lane, ah, al, acc2);
    }
    #pragma unroll
    for (int r = 0; r < 4; r++) {
        size_t rr = (size_t)(tile * 16 + quad * 4 + r) * 64 + m;
        #pragma unroll
        for (int nt = 0; nt < 4; nt++)
            hout[rr + nt * 16] = acc2[nt][r];
    }
}

// ---------------------------------------------------------------- fused pool + head
// block per graph b: binary-search node range (batch sorted), reduce, head.
__global__ __launch_bounds__(256) void k_poolhead(
    const float* __restrict__ h, const int* __restrict__ batch,
    const void* __restrict__ Wo1, const void* __restrict__ bo1,
    const void* __restrict__ Wo2, const void* __restrict__ bo2,
    const int* __restrict__ flag, void* __restrict__ out) {
    __shared__ float red[4][64];
    int b = blockIdx.x;
    int lo = 0, hi = N_NODES;
    while (lo < hi) { int mid = (lo + hi) >> 1; if (batch[mid] < b) lo = mid + 1; else hi = mid; }
    int start = lo;
    hi = N_NODES;
    while (lo < hi) { int mid = (lo + hi) >> 1; if (batch[mid] < b + 1) lo = mid + 1; else hi = mid; }
    int end = lo;
    int lane = threadIdx.x & 63;
    int w = threadIdx.x >> 6;
    float s = 0.f;
    for (int n = start + w; n < end; n += 4)
        s += h[(size_t)n * 64 + lane];
    red[w][lane] = s;
    __syncthreads();
    if (w == 0) {
        int f = *flag;
        float tot = red[0][lane] + red[1][lane] + red[2][lane] + red[3][lane];
        float c = (float)(end - start);
        float p = fmaxf(tot / fmaxf(c, 1.0f), 0.f);
        float acc = ldx(bo1, lane, f);
        #pragma unroll
        for (int kk = 0; kk < 64; kk++)
            acc += __shfl(p, kk) * ldx(Wo1, kk * 64 + lane, f);
        float t1 = fmaxf(acc, 0.f);
        float acc2 = (lane < OUT_DIM) ? ldx(bo2, lane, f) : 0.f;
        #pragma unroll
        for (int kk = 0; kk < 64; kk++) {
            float wv = (lane < OUT_DIM) ? ldx(Wo2, kk * OUT_DIM + lane, f) : 0.f;
            acc2 += __shfl(t1, kk) * wv;
        }
        if (lane < OUT_DIM) {
            if (f) ((float*)out)[b * OUT_DIM + lane] = acc2;
            else   ((bf16*)out)[b * OUT_DIM + lane] = __float2bfloat16(acc2);
        }
    }
}

extern "C" void kernel_launch(void* const* d_in, const int* in_sizes, int n_in,
                              void* d_out, int out_size, void* d_ws, size_t ws_size,
                              hipStream_t stream) {
    const int expect[19] = {
        N_NODES * 64, N_EDGES * 6, N_TRI * 6,
        L_LAYERS * 76 * 64, L_LAYERS * 64,
        L_LAYERS * 128 * 64, L_LAYERS * 64,
        L_LAYERS * 128 * 64, L_LAYERS * 64,
        L_LAYERS * 64 * 64, L_LAYERS * 64,
        64 * 64, 64, 64 * OUT_DIM, OUT_DIM,
        2 * N_EDGES, N_TRI, N_TRI, N_NODES
    };

    char* ws = (char*)d_ws;
    float* h      = (float*)(ws + 0);            // 4,096,000
    float* agg_e  = (float*)(ws + 4096000);      // 4,096,000
    float* aggr   = (float*)(ws + 8192000);      // 4,096,000
    float* X      = (float*)(ws + 12288000);     // 4,096,000 (Hh)
    float* Y      = (float*)(ws + 16384000);     // 4,096,000 (Hs)
    int*   flag   = (int*)(ws + 20480000);       // 256
    int*   cur_t  = (int*)(ws + 20480256);       // 64,000 (-> tri bucket ends)
    int*   cur_e  = (int*)(ws + 20544256);       // 64,000 (-> edge bucket ends)
    int*   k_srt  = (int*)(ws + 20608256);       // 2,560,000
    int*   src_s  = (int*)(ws + 23168256);       // 1,024,000
    float* cbf_s  = (float*)(ws + 24192256);     // 15,360,000
    const size_t FULL_NEED = 39552256u;

    const int out_n = N_B * OUT_DIM;

    int perm[19];
    bool used[64];
    for (int i = 0; i < 64; i++) used[i] = false;
    int fail_slot = -1;
    for (int i = 0; i < 19; i++) {
        perm[i] = -1;
        for (int jj = 0; jj < n_in && jj < 64; jj++) {
            if (!used[jj] && in_sizes[jj] == expect[i]) { used[jj] = true; perm[i] = jj; break; }
        }
        if (perm[i] < 0 && fail_slot < 0) fail_slot = i;
    }

    if (n_in < 19 || fail_slot >= 0 || ws_size < FULL_NEED) {
        float code = (ws_size < FULL_NEED) ? 40000.0f
                   : (n_in < 19)           ? 50000.0f
                   : 20000.0f + 1000.0f * (float)fail_slot;
        k_probe<<<1, 64, 0, stream>>>(d_in[0], (int*)d_ws);
        k_fill<<<(out_n + 255) / 256, 256, 0, stream>>>(d_out, (int*)d_ws, code, out_n);
        return;
    }

    const void* x    = d_in[perm[0]];
    const void* rbf  = d_in[perm[1]];
    const void* cbf  = d_in[perm[2]];
    const void* W1   = d_in[perm[3]];
    const void* b1   = d_in[perm[4]];
    const void* W2   = d_in[perm[5]];
    const void* b2   = d_in[perm[6]];
    const void* Wn1  = d_in[perm[7]];
    const void* bn1  = d_in[perm[8]];
    const void* Wn2  = d_in[perm[9]];
    const void* bn2  = d_in[perm[10]];
    const void* Wo1  = d_in[perm[11]];
    const void* bo1  = d_in[perm[12]];
    const void* Wo2  = d_in[perm[13]];
    const void* bo2  = d_in[perm[14]];
    const int* edge_index = (const int*)d_in[perm[15]];
    const int* k_idx = (const int*)d_in[perm[16]];
    const int* j_idx = (const int*)d_in[perm[17]];
    const int* batch = (const int*)d_in[perm[18]];

    const int TB = (N_TRI + 255) / 256;    // 2500
    const int EB = (N_EDGES + 255) / 256;  // 1000

    // 1. zero cursors + dtype probe
    k_setup<<<64, 256, 0, stream>>>(rbf, flag, cur_t);
    // 2. histograms (tri by j, edge by dst)
    k_hist2<<<TB + EB, 256, 0, stream>>>(j_idx, edge_index, cur_t, cur_e);
    // 3. exclusive scans
    k_scan2<<<2, 256, 0, stream>>>(cur_t, cur_e);
    // 4. scatter + payload gather (k_srt, cbf_s f32, src_s); cursors become ends
    k_scatter2<<<TB + EB, 256, 0, stream>>>(j_idx, k_idx, cbf, edge_index,
                                            cur_t, cur_e, k_srt, cbf_s, src_s, flag);

    const void* hc = x;  // layer 0 reads x directly (dual-dtype)
    int hws = 0;
    for (int l = 0; l < L_LAYERS; l++) {
        size_t offW1l = (size_t)l * 76 * 64;
        size_t offW2l = (size_t)l * 128 * 64;
        size_t offWn2 = (size_t)l * 64 * 64;
        size_t offB   = (size_t)l * 64;
        // Hh -> X, Hs -> Y (one pass over h)
        k_lin2out<<<250, 256, 0, stream>>>(hc, hws, W1, offW1l, b1,
                                           W2, offW2l, b2, offB, flag, X, Y);
        // agg_e = segsum_j relu(Hh[k] + rbf[j]@W1r + cbf@W1c)
        k_tri_seg<<<4000, 256, 0, stream>>>(cur_t, k_srt, cbf_s, X, rbf,
                                            W1, offW1l, flag, agg_e);
        // aggr = segsum_d relu(Hs[src] + (agg_e[d] @ W2a))
        k_edge_f<<<4000, 256, 0, stream>>>(cur_e, src_s, Y, agg_e,
                                           W2, offW2l + 64 * 64, flag, aggr);
        // h' = relu([h|aggr]@Wn1+bn1)@Wn2+bn2
        k_node_f<<<250, 256, 0, stream>>>(hc, hws, aggr, Wn1, bn1, Wn2, bn2,
                                          offW2l, offB, offWn2, flag, h);
        hc = h; hws = 1;
    }
    // pool + head fused (batch sorted -> contiguous per-graph ranges)
    k_poolhead<<<N_B, 256, 0, stream>>>(h, batch, Wo1, bo1, Wo2, bo2, flag, d_out);
}